// Round 3
// baseline (299.640 us; speedup 1.0000x reference)
//
#include <hip/hip_runtime.h>
#include <math.h>

#define TPB 256

// Round-0 structure (coalesced 16-lane-per-row groups, weights transposed in
// LDS) but each group owns TWO rows: halves ds_read_b128 per row (18.4->9.2,
// DS pipe ~72% -> ~36% of the HBM budget) while keeping the resident-wave
// count identical to round 0 (32-row blocks -> 2048 blocks -> 8 blocks/CU x
// 4 waves = 32 waves/CU; LDS 19KB -> 8 blocks resident). Round-1's 4-rows
// variant confounded the DS cut with a 4x drop in blocks/CU — this version
// deconfounds.
__global__ __launch_bounds__(TPB) void hybrid_kernel(
    const float* __restrict__ inp,   // (B, 784)
    const float* __restrict__ dw,    // (784, 6)
    const float* __restrict__ db,    // (6,)
    const float* __restrict__ qw,    // (15,)
    const float* __restrict__ ow,    // (6, 1)
    const float* __restrict__ ob,    // (1,)
    float* __restrict__ out,         // (B, 1)
    int B)
{
    __shared__ float4 wT4[6 * 196];          // wT[j][e] as float4 along e
    __shared__ float csc[15], css[15];
    __shared__ float sb[8], sw[8];
    __shared__ float sob;

    float* wT = (float*)wT4;
    const int tid = threadIdx.x;

    // ---- once per block: transpose dense_w into LDS, precompute cos/sin ----
    for (int i = tid; i < 4704; i += TPB) {   // 784*6
        int e = i / 6;
        int j = i - e * 6;
        wT[j * 784 + e] = dw[i];
    }
    if (tid < 15) { float q = qw[tid]; csc[tid] = cosf(q); css[tid] = sinf(q); }
    if (tid < 6)  { sb[tid] = db[tid]; sw[tid] = ow[tid]; }
    if (tid == 0) sob = ob[0];
    __syncthreads();

    const int lane = tid & 63;
    const int grp  = lane >> 4;       // 0..3 : which row-pair within the wave
    const int gl   = lane & 15;       // lane within the 16-lane group
    const int rowA = blockIdx.x * 32 + (tid >> 6) * 8 + grp * 2;
    if (rowA >= B) return;            // no further barriers below
    const int rowB = (rowA + 1 < B) ? rowA + 1 : rowA;

    const float4* xA = (const float4*)(inp + (size_t)rowA * 784);
    const float4* xB = (const float4*)(inp + (size_t)rowB * 784);

    float acc[2][6] = {};

    // 196 float4 per row: 12 full passes of 16 lanes + 4-lane tail
    #pragma unroll 4
    for (int t = 0; t < 12; ++t) {
        const int idx4 = gl + 16 * t;
        const float4 a0 = xA[idx4];
        const float4 a1 = xB[idx4];
        #pragma unroll
        for (int j = 0; j < 6; ++j) {
            const float4 wv = wT4[j * 196 + idx4];
            acc[0][j] += a0.x * wv.x + a0.y * wv.y + a0.z * wv.z + a0.w * wv.w;
            acc[1][j] += a1.x * wv.x + a1.y * wv.y + a1.z * wv.z + a1.w * wv.w;
        }
    }
    if (gl < 4) {
        const int idx4 = 192 + gl;
        const float4 a0 = xA[idx4];
        const float4 a1 = xB[idx4];
        #pragma unroll
        for (int j = 0; j < 6; ++j) {
            const float4 wv = wT4[j * 196 + idx4];
            acc[0][j] += a0.x * wv.x + a0.y * wv.y + a0.z * wv.z + a0.w * wv.w;
            acc[1][j] += a1.x * wv.x + a1.y * wv.y + a1.z * wv.z + a1.w * wv.w;
        }
    }

    // reduce across the 16-lane group (masks 1,2,4,8 stay inside the group)
    #pragma unroll
    for (int m = 1; m <= 8; m <<= 1) {
        #pragma unroll
        for (int r = 0; r < 2; ++r) {
            #pragma unroll
            for (int j = 0; j < 6; ++j)
                acc[r][j] += __shfl_xor(acc[r][j], m, 64);
        }
    }

    // ---- epilogue per row (redundant across the 16 lanes; gl==0 stores) ----
    // PYRAMID_PAIRS: second index is always first+1
    const int PI[15] = {0,1,0,2,1,3,0,2,4,1,3,0,2,1,0};

    #pragma unroll
    for (int r = 0; r < 2; ++r) {
        float a[6];
        float hh = 0.f;
        #pragma unroll
        for (int j = 0; j < 6; ++j) {
            a[j] = acc[r][j] + sb[j];
            hh += a[j] * a[j];
        }
        const float inv = rsqrtf(hh);   // hh==0 -> inf -> NaN downstream, matches ref
        float an[6];
        #pragma unroll
        for (int j = 0; j < 6; ++j) an[j] = a[j] * inv;

        #pragma unroll
        for (int k = 0; k < 15; ++k) {
            const int i = PI[k];
            const float c = csc[k], s = css[k];
            const float ai = an[i], aj = an[i + 1];
            an[i]     = c * ai + s * aj;
            an[i + 1] = c * aj - s * ai;
        }

        float v = sob;
        #pragma unroll
        for (int j = 0; j < 6; ++j) {
            float z = 1.f - 2.f * an[j] * an[j];
            z = isnan(z) ? 0.f : z;     // jnp.where(isnan(z), 0, z)
            v += z * sw[j];
        }
        const float o = 1.f / (1.f + __expf(-v));

        if (gl == 0 && rowA + r < B) out[rowA + r] = o;
    }
}

extern "C" void kernel_launch(void* const* d_in, const int* in_sizes, int n_in,
                              void* d_out, int out_size, void* d_ws, size_t ws_size,
                              hipStream_t stream) {
    const float* inp = (const float*)d_in[0];
    const float* dw  = (const float*)d_in[1];
    const float* db  = (const float*)d_in[2];
    const float* qw  = (const float*)d_in[3];
    const float* ow  = (const float*)d_in[4];
    const float* ob  = (const float*)d_in[5];
    float* out = (float*)d_out;

    const int B = in_sizes[0] / 784;          // 65536
    const int blocks = (B + 31) / 32;         // 32 rows per block
    hybrid_kernel<<<blocks, TPB, 0, stream>>>(inp, dw, db, qw, ow, ob, out, B);
}